// Round 9
// baseline (987.702 us; speedup 1.0000x reference)
//
#include <hip/hip_runtime.h>
#include <hip/hip_fp16.h>
#include <math.h>

// Problem constants
#define NB 2048      // batch
#define ND 1024      // dim
#define EPS 0.05f
#define NITER 100
#define SBLK 64      // sinkhorn blocks x 512 threads; 32 rows/block
#define KSCALE 16384.0f               // 2^14 — pulls f16 K into normal range
#define LOG_KSCALE 9.704060527839234  // log(2^14)

typedef float f32x4 __attribute__((ext_vector_type(4)));
typedef short s16x8 __attribute__((ext_vector_type(8)));
typedef unsigned short u16x4 __attribute__((ext_vector_type(4)));
typedef _Float16 h16x2 __attribute__((ext_vector_type(2)));
union Uh { f32x4 f; __half2 h[4]; };
union Uk { f32x4 f; h16x2 h[4]; };

#if defined(__has_builtin)
#if __has_builtin(__builtin_amdgcn_fdot2)
#define HAVE_FDOT2 1
#endif
#endif

// ---------------- prep: w = nan_to_num(diag(L)), init u/v, zero flags+max ----------------
__global__ void prep_k(const float* __restrict__ L, float* __restrict__ w,
                       float* __restrict__ u, float* __restrict__ v,
                       unsigned* __restrict__ maxbits, unsigned* __restrict__ flags) {
    int gtid = blockIdx.x * 256 + threadIdx.x;   // 0..2047
    if (gtid < ND) {
        float x = L[(size_t)gtid * (ND + 1)];
        if (x != x) x = 0.f;
        else if (fabsf(x) == INFINITY) x = (x > 0.f) ? 3.4028235e38f : -3.4028235e38f;
        w[gtid] = x;
    }
    u[gtid] = 1.0f / NB;
    v[gtid] = 1.0f / NB;
    if (gtid == 0) *maxbits = 0u;
    if (gtid < 512) flags[gtid] = 0u;
}

// ---------------- per-row weighted squared norms ----------------
__global__ __launch_bounds__(256) void rows_k(const float* __restrict__ audio,
                                              const float* __restrict__ text,
                                              const float* __restrict__ w,
                                              float* __restrict__ aw, float* __restrict__ tw) {
    int r = blockIdx.x, tid = threadIdx.x;
    float4 wv = *(const float4*)&w[tid * 4];
    float4 a4 = *(const float4*)&audio[(size_t)r * ND + tid * 4];
    float4 t4 = *(const float4*)&text[(size_t)r * ND + tid * 4];
    float sa = a4.x * a4.x * wv.x + a4.y * a4.y * wv.y + a4.z * a4.z * wv.z + a4.w * a4.w * wv.w;
    float st = t4.x * t4.x * wv.x + t4.y * t4.y * wv.y + t4.z * t4.z * wv.z + t4.w * t4.w * wv.w;
    #pragma unroll
    for (int off = 32; off; off >>= 1) {
        sa += __shfl_down(sa, off, 64);
        st += __shfl_down(st, off, 64);
    }
    __shared__ float red[8];
    if ((tid & 63) == 0) { red[tid >> 6] = sa; red[4 + (tid >> 6)] = st; }
    __syncthreads();
    if (tid == 0) {
        aw[r] = red[0] + red[1] + red[2] + red[3];
        tw[r] = red[4] + red[5] + red[6] + red[7];
    }
}

// ---------------- f32 -> bf16 round-to-nearest-even (bit trick) ----------------
__device__ __forceinline__ unsigned short f2bf(float x) {
    unsigned uu = __float_as_uint(x);
    return (unsigned short)((uu + 0x7FFFu + ((uu >> 16) & 1u)) >> 16);
}

// ---------------- bf16 MFMA GEMM -> M_dist (f16, row + col major) + global max ----------------
__global__ __launch_bounds__(256) void gemm_mdist(
        const float* __restrict__ Tm, const float* __restrict__ Am,
        const float* __restrict__ wd, const float* __restrict__ tw, const float* __restrict__ aw,
        __half* __restrict__ Md, __half* __restrict__ MdT,
        float* __restrict__ diagMd, unsigned* __restrict__ maxbits) {
    __shared__ __align__(16) unsigned char smem[38912];
    float* wl = (float*)(smem + 34816);
    const int t = threadIdx.x;
    const int row0 = blockIdx.y * 128, col0 = blockIdx.x * 128;
    *(f32x4*)&wl[t * 4] = *(const f32x4*)&wd[t * 4];
    const int wv = t >> 6;                 // wave 0..3
    const int wr = wv >> 1, wc = wv & 1;   // 2x2 wave grid, 64x64 out each
    const int l = t & 63, lr = l & 15, kg = l >> 4;
    const int trow = t >> 4, tk4 = t & 15;
    const int px = (((tk4 >> 1) ^ (trow & 7)) << 4) + ((tk4 & 1) << 3);
    f32x4 acc[4][4];
    #pragma unroll
    for (int m = 0; m < 4; ++m)
        #pragma unroll
        for (int n = 0; n < 4; ++n) acc[m][n] = (f32x4){0.f, 0.f, 0.f, 0.f};
    __syncthreads();
    const float* tp = Tm + (size_t)(row0 + trow) * ND + tk4 * 4;
    const float* ap = Am + (size_t)(col0 + trow) * ND + tk4 * 4;
    for (int k0 = 0; k0 < ND; k0 += 64) {
        f32x4 wv4 = *(const f32x4*)&wl[k0 + tk4 * 4];
        __syncthreads();
        #pragma unroll
        for (int s = 0; s < 8; ++s) {
            f32x4 tv = *(const f32x4*)(tp + (size_t)(s * 16) * ND + k0);
            f32x4 av = *(const f32x4*)(ap + (size_t)(s * 16) * ND + k0);
            tv *= wv4;
            u16x4 tb, ab;
            tb[0] = f2bf(tv[0]); tb[1] = f2bf(tv[1]); tb[2] = f2bf(tv[2]); tb[3] = f2bf(tv[3]);
            ab[0] = f2bf(av[0]); ab[1] = f2bf(av[1]); ab[2] = f2bf(av[2]); ab[3] = f2bf(av[3]);
            const int rb = (s * 16 + trow) * 128 + px;
            *(u16x4*)(smem + rb) = tb;
            *(u16x4*)(smem + 16384 + rb) = ab;
        }
        __syncthreads();
        #pragma unroll
        for (int kk = 0; kk < 2; ++kk) {
            const int sl = (((kk << 2) + kg) ^ (lr & 7)) << 4;
            s16x8 af[4], bfr[4];
            #pragma unroll
            for (int m = 0; m < 4; ++m)
                af[m] = *(const s16x8*)(smem + (wr * 64 + m * 16 + lr) * 128 + sl);
            #pragma unroll
            for (int n = 0; n < 4; ++n)
                bfr[n] = *(const s16x8*)(smem + 16384 + (wc * 64 + n * 16 + lr) * 128 + sl);
            #pragma unroll
            for (int m = 0; m < 4; ++m)
                #pragma unroll
                for (int n = 0; n < 4; ++n)
                    acc[m][n] = __builtin_amdgcn_mfma_f32_16x16x32_bf16(af[m], bfr[n], acc[m][n], 0, 0, 0);
        }
    }
    __syncthreads();
    unsigned short* tr = (unsigned short*)smem;
    unsigned short* mdp = (unsigned short*)Md;
    float lmax = 0.f;
    #pragma unroll
    for (int m = 0; m < 4; ++m) {
        #pragma unroll
        for (int r = 0; r < 4; ++r) {
            const int li = wr * 64 + m * 16 + kg * 4 + r;
            const int i = row0 + li;
            const float twi = tw[i];
            #pragma unroll
            for (int n = 0; n < 4; ++n) {
                const int lj = wc * 64 + n * 16 + lr;
                const int j = col0 + lj;
                float md = twi + aw[j] - 2.0f * acc[m][n][r];
                md = sqrtf(fmaxf(md, 0.f));
                lmax = fmaxf(lmax, md);
                const unsigned short hb = __half_as_ushort(__float2half(md));
                mdp[(size_t)i * NB + j] = hb;
                tr[lj * 136 + li] = hb;
                if (i == j) diagMd[i] = md;
            }
        }
    }
    __syncthreads();
    {
        const int jj = t >> 1, ih = (t & 1) * 64;
        unsigned short* dst = (unsigned short*)MdT + (size_t)(col0 + jj) * NB + row0 + ih;
        #pragma unroll
        for (int x = 0; x < 8; ++x)
            *(s16x8*)(dst + x * 8) = *(const s16x8*)&tr[jj * 136 + ih + x * 8];
    }
    #pragma unroll
    for (int off = 32; off; off >>= 1) lmax = fmaxf(lmax, __shfl_down(lmax, off, 64));
    float* red = (float*)(smem + 34816);
    if (l == 0) red[t >> 6] = lmax;
    __syncthreads();
    if (t == 0) {
        float m2 = fmaxf(fmaxf(red[0], red[1]), fmaxf(red[2], red[3]));
        atomicMax(maxbits, __float_as_uint(m2));
    }
}

// ---------------- convert M_dist -> K' = exp(-md/(mx*eps)) * 2^14, in place (both majors) ----------------
__global__ __launch_bounds__(256) void expconv_k(__half* __restrict__ Kall,
                                                 const unsigned* __restrict__ maxbits) {
    const float mx = __uint_as_float(*maxbits);
    const float cc = -1.0f / (mx * EPS);
    size_t idx = ((size_t)blockIdx.x * 256 + threadIdx.x) << 3;   // 8 halfs per thread
    Uh uu; uu.f = *(const f32x4*)(Kall + idx);
    #pragma unroll
    for (int q = 0; q < 4; ++q) {
        float2 f = __half22float2(uu.h[q]);
        f.x = __expf(f.x * cc) * KSCALE;
        f.y = __expf(f.y * cc) * KSCALE;
        uu.h[q] = __floats2half2_rn(f.x, f.y);
    }
    *(f32x4*)(Kall + idx) = uu.f;
}

// ---------------- store-broadcast barrier: 64 flags (16B apart), no RMW anywhere ----------------
// wave 0 polls: lane l loads flags[l*4]; all lanes' flags >= ph -> done.
__device__ __forceinline__ void wait_phase(const unsigned* __restrict__ pollp, int w, unsigned ph) {
    if (w == 0) {
        for (;;) {
            unsigned f;
            asm volatile("global_load_dword %0, %1, off sc0 sc1\n\t"
                         "s_waitcnt vmcnt(0)"
                         : "=&v"(f) : "v"(pollp) : "memory");
            if (__all(f >= ph)) break;
            __builtin_amdgcn_s_sleep(1);
        }
    }
}

// ---------------- LLC-coherent stage: 512 threads x 4 floats -> f16 pairs in LDS ----------------
__device__ __forceinline__ void stage(const float* __restrict__ src, unsigned short* svh, int tid) {
    const float* p0 = src + (tid << 2);
    f32x4 r0;
    asm volatile("global_load_dwordx4 %0, %1, off sc0 sc1\n\t"
                 "s_waitcnt vmcnt(0)"
                 : "=&v"(r0) : "v"(p0) : "memory");
    h16x2 a, b;
    a[0] = (_Float16)r0[0]; a[1] = (_Float16)r0[1];
    b[0] = (_Float16)r0[2]; b[1] = (_Float16)r0[3];
    *(h16x2*)&svh[(tid << 2)] = a;
    *(h16x2*)&svh[(tid << 2) + 2] = b;
}

// ---------------- one half-step: xout[row0..3] = ab / (K[rows] . sv); dot2 inner loop ----------------
__device__ __forceinline__ void half_step(const __half* __restrict__ Kmat,
                                          float* __restrict__ xout,
                                          const unsigned short* svh, int row0, float ab, int l) {
    float acc[4] = {0.f, 0.f, 0.f, 0.f};
    const unsigned short* kb = (const unsigned short*)(Kmat + (size_t)row0 * NB);
    #pragma unroll
    for (int c = 0; c < 4; ++c) {
        const int col = (c << 9) + (l << 3);           // lane covers 4 chunks of 8 cols
        Uk s; s.f = *(const f32x4*)&svh[col];          // ds_read_b128: 8 halfs of sv
        #pragma unroll
        for (int r = 0; r < 4; ++r) {
            Uk k; k.f = *(const f32x4*)(kb + (size_t)r * NB + col);   // plain cached K loads
#ifdef HAVE_FDOT2
            acc[r] = __builtin_amdgcn_fdot2(k.h[0], s.h[0], acc[r], false);
            acc[r] = __builtin_amdgcn_fdot2(k.h[1], s.h[1], acc[r], false);
            acc[r] = __builtin_amdgcn_fdot2(k.h[2], s.h[2], acc[r], false);
            acc[r] = __builtin_amdgcn_fdot2(k.h[3], s.h[3], acc[r], false);
#else
            #pragma unroll
            for (int q = 0; q < 4; ++q) {
                acc[r] = fmaf((float)k.h[q][0], (float)s.h[q][0], acc[r]);
                acc[r] = fmaf((float)k.h[q][1], (float)s.h[q][1], acc[r]);
            }
#endif
        }
    }
    #pragma unroll
    for (int r = 0; r < 4; ++r) {
        #pragma unroll
        for (int off = 32; off; off >>= 1) acc[r] += __shfl_down(acc[r], off, 64);
    }
    if (l == 0) {
        f32x4 o;
        o[0] = ab / acc[0]; o[1] = ab / acc[1]; o[2] = ab / acc[2]; o[3] = ab / acc[3];
        asm volatile("global_store_dwordx4 %1, %0, off sc0 sc1"
                     :: "v"(o), "v"(xout + row0) : "memory");
    }
    asm volatile("s_waitcnt vmcnt(0)" ::: "memory");   // wave-wide drain before the barrier
}

// ---------------- persistent Sinkhorn: 100 x { v = b/(K^T u); u = a/(K v) } ----------------
// 64 blocks x 8 waves x 4 rows. Arrivals are single stores to per-block flags
// (monotonic, no RMW, no acquire/release -> no L2 invalidates ever).
__global__ __launch_bounds__(512, 1) void sinkhorn_k(
        const __half* __restrict__ Kr, const __half* __restrict__ Kc,
        float* __restrict__ u, float* __restrict__ v,
        unsigned* __restrict__ flags) {
    __shared__ __align__(16) unsigned short svh[2048];   // staged vector as f16 (4KB)
    const int tid = threadIdx.x, bid = blockIdx.x;
    const int w = tid >> 6, l = tid & 63;
    const int row0 = ((bid << 3) + w) << 2;    // 32 rows/block, 4 rows/wave
    const float ab = 1.0f / NB;
    unsigned* myflag = flags + (bid << 2);                 // 16B apart
    const unsigned* pollp = flags + ((l & 63) << 2);       // lane l -> block l's flag
    for (int it = 0; it < NITER; ++it) {
        // ---- v-step: v = b / (K^T u); needs u@it (phase 2it) ----
        wait_phase(pollp, w, 2 * it);
        __syncthreads();                       // release block; also fences prior svh reads
        stage(u, svh, tid);
        __syncthreads();
        half_step(Kc, v, svh, row0, ab, l);    // compute + store + wave drain
        __syncthreads();                       // all waves' stores drained
        if (tid == 0) {
            unsigned ph = 2 * it + 1;
            asm volatile("global_store_dword %1, %0, off sc0 sc1"
                         :: "v"(ph), "v"(myflag) : "memory");
        }
        // ---- u-step: u = a / (K v); needs v@it+1 (phase 2it+1) ----
        wait_phase(pollp, w, 2 * it + 1);
        __syncthreads();
        stage(v, svh, tid);
        __syncthreads();
        half_step(Kr, u, svh, row0, ab, l);
        __syncthreads();
        if (tid == 0) {
            unsigned ph = 2 * it + 2;
            asm volatile("global_store_dword %1, %0, off sc0 sc1"
                         :: "v"(ph), "v"(myflag) : "memory");
        }
    }
}

// ---------------- loss: -(1/B) * sum_i [log u_i + log v_i + log K_ii] - log(2^14) ----------------
__global__ void loss_k(const float* __restrict__ u, const float* __restrict__ v,
                       const float* __restrict__ diagMd, const unsigned* __restrict__ maxbits,
                       float* __restrict__ out) {
    int tid = threadIdx.x;
    float mx = __uint_as_float(*maxbits);
    float cc = 1.0f / (mx * EPS);
    double s = 0.0;
    for (int i = tid; i < NB; i += 256)
        s += (double)(logf(u[i]) + logf(v[i]) - diagMd[i] * cc);
    #pragma unroll
    for (int off = 32; off; off >>= 1) s += __shfl_down(s, off, 64);
    __shared__ double red[4];
    if ((tid & 63) == 0) red[tid >> 6] = s;
    __syncthreads();
    if (tid == 0)
        out[0] = (float)(-(red[0] + red[1] + red[2] + red[3]) / (double)NB - LOG_KSCALE);
}

// ---------------- launch ----------------
extern "C" void kernel_launch(void* const* d_in, const int* in_sizes, int n_in,
                              void* d_out, int out_size, void* d_ws, size_t ws_size,
                              hipStream_t stream) {
    const float* audio = (const float*)d_in[0];
    const float* text  = (const float*)d_in[1];
    const float* L     = (const float*)d_in[2];
    char* ws = (char*)d_ws;
    float*    w       = (float*)(ws + 0);
    float*    aw      = (float*)(ws + 4096);
    float*    tw      = (float*)(ws + 12288);
    float*    u       = (float*)(ws + 20480);
    float*    v       = (float*)(ws + 28672);
    float*    diagMd  = (float*)(ws + 36864);
    unsigned* maxbits = (unsigned*)(ws + 45056);
    unsigned* flags   = (unsigned*)(ws + 45312);
    __half*   Md      = (__half*)(ws + 65536);                          // becomes Kr
    __half*   MdT     = (__half*)(ws + 65536 + (size_t)NB * NB * 2);    // becomes Kc

    prep_k<<<8, 256, 0, stream>>>(L, w, u, v, maxbits, flags);
    rows_k<<<NB, 256, 0, stream>>>(audio, text, w, aw, tw);
    gemm_mdist<<<dim3(16, 16), 256, 0, stream>>>(text, audio, w, tw, aw, Md, MdT, diagMd, maxbits);
    expconv_k<<<4096, 256, 0, stream>>>(Md, maxbits);   // Md & MdT contiguous: 2*NB*NB halfs
    sinkhorn_k<<<SBLK, 512, 0, stream>>>(Md, MdT, u, v, flags);
    loss_k<<<1, 256, 0, stream>>>(u, v, diagMd, maxbits, (float*)d_out);
}

// Round 10
// 761.310 us; speedup vs baseline: 1.2974x; 1.2974x over previous
//
#include <hip/hip_runtime.h>
#include <hip/hip_fp16.h>
#include <math.h>

// Problem constants
#define NB 2048      // batch
#define ND 1024      // dim
#define EPS 0.05f
#define NITER 100
#define SBLK 256     // sinkhorn blocks x 256 threads; 8 rows/block, full chip
#define KSCALE 16384.0f               // 2^14 — pulls f16 K into normal range
#define LOG_KSCALE 9.704060527839234  // log(2^14)

typedef float f32x4 __attribute__((ext_vector_type(4)));
typedef float f32x2 __attribute__((ext_vector_type(2)));
typedef short s16x8 __attribute__((ext_vector_type(8)));
typedef unsigned short u16x4 __attribute__((ext_vector_type(4)));
union Uh { f32x4 f; __half2 h[4]; };

// ---------------- prep: w = nan_to_num(diag(L)), init u/v, zero flags+max ----------------
__global__ void prep_k(const float* __restrict__ L, float* __restrict__ w,
                       float* __restrict__ u, float* __restrict__ v,
                       unsigned* __restrict__ maxbits, unsigned* __restrict__ flags) {
    int gtid = blockIdx.x * 256 + threadIdx.x;   // 0..2047
    if (gtid < ND) {
        float x = L[(size_t)gtid * (ND + 1)];
        if (x != x) x = 0.f;
        else if (fabsf(x) == INFINITY) x = (x > 0.f) ? 3.4028235e38f : -3.4028235e38f;
        w[gtid] = x;
    }
    u[gtid] = 1.0f / NB;
    v[gtid] = 1.0f / NB;
    if (gtid == 0) *maxbits = 0u;
    if (gtid < 1024) flags[gtid] = 0u;   // 256 flags x 16B
}

// ---------------- per-row weighted squared norms ----------------
__global__ __launch_bounds__(256) void rows_k(const float* __restrict__ audio,
                                              const float* __restrict__ text,
                                              const float* __restrict__ w,
                                              float* __restrict__ aw, float* __restrict__ tw) {
    int r = blockIdx.x, tid = threadIdx.x;
    float4 wv = *(const float4*)&w[tid * 4];
    float4 a4 = *(const float4*)&audio[(size_t)r * ND + tid * 4];
    float4 t4 = *(const float4*)&text[(size_t)r * ND + tid * 4];
    float sa = a4.x * a4.x * wv.x + a4.y * a4.y * wv.y + a4.z * a4.z * wv.z + a4.w * a4.w * wv.w;
    float st = t4.x * t4.x * wv.x + t4.y * t4.y * wv.y + t4.z * t4.z * wv.z + t4.w * t4.w * wv.w;
    #pragma unroll
    for (int off = 32; off; off >>= 1) {
        sa += __shfl_down(sa, off, 64);
        st += __shfl_down(st, off, 64);
    }
    __shared__ float red[8];
    if ((tid & 63) == 0) { red[tid >> 6] = sa; red[4 + (tid >> 6)] = st; }
    __syncthreads();
    if (tid == 0) {
        aw[r] = red[0] + red[1] + red[2] + red[3];
        tw[r] = red[4] + red[5] + red[6] + red[7];
    }
}

// ---------------- f32 -> bf16 round-to-nearest-even (bit trick) ----------------
__device__ __forceinline__ unsigned short f2bf(float x) {
    unsigned uu = __float_as_uint(x);
    return (unsigned short)((uu + 0x7FFFu + ((uu >> 16) & 1u)) >> 16);
}

// ---------------- bf16 MFMA GEMM -> M_dist (f16, row + col major) + global max ----------------
__global__ __launch_bounds__(256) void gemm_mdist(
        const float* __restrict__ Tm, const float* __restrict__ Am,
        const float* __restrict__ wd, const float* __restrict__ tw, const float* __restrict__ aw,
        __half* __restrict__ Md, __half* __restrict__ MdT,
        float* __restrict__ diagMd, unsigned* __restrict__ maxbits) {
    __shared__ __align__(16) unsigned char smem[38912];
    float* wl = (float*)(smem + 34816);
    const int t = threadIdx.x;
    const int row0 = blockIdx.y * 128, col0 = blockIdx.x * 128;
    *(f32x4*)&wl[t * 4] = *(const f32x4*)&wd[t * 4];
    const int wv = t >> 6;                 // wave 0..3
    const int wr = wv >> 1, wc = wv & 1;   // 2x2 wave grid, 64x64 out each
    const int l = t & 63, lr = l & 15, kg = l >> 4;
    const int trow = t >> 4, tk4 = t & 15;
    const int px = (((tk4 >> 1) ^ (trow & 7)) << 4) + ((tk4 & 1) << 3);
    f32x4 acc[4][4];
    #pragma unroll
    for (int m = 0; m < 4; ++m)
        #pragma unroll
        for (int n = 0; n < 4; ++n) acc[m][n] = (f32x4){0.f, 0.f, 0.f, 0.f};
    __syncthreads();
    const float* tp = Tm + (size_t)(row0 + trow) * ND + tk4 * 4;
    const float* ap = Am + (size_t)(col0 + trow) * ND + tk4 * 4;
    for (int k0 = 0; k0 < ND; k0 += 64) {
        f32x4 wv4 = *(const f32x4*)&wl[k0 + tk4 * 4];
        __syncthreads();
        #pragma unroll
        for (int s = 0; s < 8; ++s) {
            f32x4 tv = *(const f32x4*)(tp + (size_t)(s * 16) * ND + k0);
            f32x4 av = *(const f32x4*)(ap + (size_t)(s * 16) * ND + k0);
            tv *= wv4;
            u16x4 tb, ab;
            tb[0] = f2bf(tv[0]); tb[1] = f2bf(tv[1]); tb[2] = f2bf(tv[2]); tb[3] = f2bf(tv[3]);
            ab[0] = f2bf(av[0]); ab[1] = f2bf(av[1]); ab[2] = f2bf(av[2]); ab[3] = f2bf(av[3]);
            const int rb = (s * 16 + trow) * 128 + px;
            *(u16x4*)(smem + rb) = tb;
            *(u16x4*)(smem + 16384 + rb) = ab;
        }
        __syncthreads();
        #pragma unroll
        for (int kk = 0; kk < 2; ++kk) {
            const int sl = (((kk << 2) + kg) ^ (lr & 7)) << 4;
            s16x8 af[4], bfr[4];
            #pragma unroll
            for (int m = 0; m < 4; ++m)
                af[m] = *(const s16x8*)(smem + (wr * 64 + m * 16 + lr) * 128 + sl);
            #pragma unroll
            for (int n = 0; n < 4; ++n)
                bfr[n] = *(const s16x8*)(smem + 16384 + (wc * 64 + n * 16 + lr) * 128 + sl);
            #pragma unroll
            for (int m = 0; m < 4; ++m)
                #pragma unroll
                for (int n = 0; n < 4; ++n)
                    acc[m][n] = __builtin_amdgcn_mfma_f32_16x16x32_bf16(af[m], bfr[n], acc[m][n], 0, 0, 0);
        }
    }
    __syncthreads();
    unsigned short* tr = (unsigned short*)smem;
    unsigned short* mdp = (unsigned short*)Md;
    float lmax = 0.f;
    #pragma unroll
    for (int m = 0; m < 4; ++m) {
        #pragma unroll
        for (int r = 0; r < 4; ++r) {
            const int li = wr * 64 + m * 16 + kg * 4 + r;
            const int i = row0 + li;
            const float twi = tw[i];
            #pragma unroll
            for (int n = 0; n < 4; ++n) {
                const int lj = wc * 64 + n * 16 + lr;
                const int j = col0 + lj;
                float md = twi + aw[j] - 2.0f * acc[m][n][r];
                md = sqrtf(fmaxf(md, 0.f));
                lmax = fmaxf(lmax, md);
                const unsigned short hb = __half_as_ushort(__float2half(md));
                mdp[(size_t)i * NB + j] = hb;
                tr[lj * 136 + li] = hb;
                if (i == j) diagMd[i] = md;
            }
        }
    }
    __syncthreads();
    {
        const int jj = t >> 1, ih = (t & 1) * 64;
        unsigned short* dst = (unsigned short*)MdT + (size_t)(col0 + jj) * NB + row0 + ih;
        #pragma unroll
        for (int x = 0; x < 8; ++x)
            *(s16x8*)(dst + x * 8) = *(const s16x8*)&tr[jj * 136 + ih + x * 8];
    }
    #pragma unroll
    for (int off = 32; off; off >>= 1) lmax = fmaxf(lmax, __shfl_down(lmax, off, 64));
    float* red = (float*)(smem + 34816);
    if (l == 0) red[t >> 6] = lmax;
    __syncthreads();
    if (t == 0) {
        float m2 = fmaxf(fmaxf(red[0], red[1]), fmaxf(red[2], red[3]));
        atomicMax(maxbits, __float_as_uint(m2));
    }
}

// ---------------- convert M_dist -> K' = exp(-md/(mx*eps)) * 2^14, in place (both majors) ----------------
__global__ __launch_bounds__(256) void expconv_k(__half* __restrict__ Kall,
                                                 const unsigned* __restrict__ maxbits) {
    const float mx = __uint_as_float(*maxbits);
    const float cc = -1.0f / (mx * EPS);
    size_t idx = ((size_t)blockIdx.x * 256 + threadIdx.x) << 3;   // 8 halfs per thread
    Uh uu; uu.f = *(const f32x4*)(Kall + idx);
    #pragma unroll
    for (int q = 0; q < 4; ++q) {
        float2 f = __half22float2(uu.h[q]);
        f.x = __expf(f.x * cc) * KSCALE;
        f.y = __expf(f.y * cc) * KSCALE;
        uu.h[q] = __floats2half2_rn(f.x, f.y);
    }
    *(f32x4*)(Kall + idx) = uu.f;
}

// ---------------- store-broadcast barrier: 256 flags (16B apart), no RMW anywhere ----------------
// wave 0 polls: lane l loads flags l, l+64, l+128, l+192; all >= ph -> done.
__device__ __forceinline__ void wait_phase(const unsigned* __restrict__ flags, int w, int l,
                                           unsigned ph) {
    if (w == 0) {
        const unsigned* p = flags + (l << 2);
        for (;;) {
            unsigned f0, f1, f2, f3;
            asm volatile("global_load_dword %0, %4, off sc0 sc1\n\t"
                         "global_load_dword %1, %5, off sc0 sc1\n\t"
                         "global_load_dword %2, %6, off sc0 sc1\n\t"
                         "global_load_dword %3, %7, off sc0 sc1\n\t"
                         "s_waitcnt vmcnt(0)"
                         : "=&v"(f0), "=&v"(f1), "=&v"(f2), "=&v"(f3)
                         : "v"(p), "v"(p + 256), "v"(p + 512), "v"(p + 768) : "memory");
            if (__all((f0 >= ph) && (f1 >= ph) && (f2 >= ph) && (f3 >= ph))) break;
            __builtin_amdgcn_s_sleep(1);
        }
    }
}

// ---------------- LLC-coherent 32B staged load into padded LDS ----------------
__device__ __forceinline__ void stage(const float* __restrict__ src, float* sv, int tid) {
    const float* p0 = src + (tid << 3);
    f32x4 r0, r1;
    asm volatile("global_load_dwordx4 %0, %2, off sc0 sc1\n\t"
                 "global_load_dwordx4 %1, %3, off sc0 sc1\n\t"
                 "s_waitcnt vmcnt(0)"
                 : "=&v"(r0), "=&v"(r1) : "v"(p0), "v"(p0 + 4) : "memory");
    // padded LDS layout: logical i -> i + (i/8)*4  (conflict-free b128 reads)
    *(f32x4*)&sv[tid * 12] = r0;
    *(f32x4*)&sv[tid * 12 + 4] = r1;
}

// ---------------- one half-step: xout[row0..1] = ab / (K[rows] . sv); lane0 8B store ----------------
__device__ __forceinline__ void half_step(const __half* __restrict__ Kmat,
                                          float* __restrict__ xout,
                                          const float* sv, int row0, float ab, int l) {
    float acc[2] = {0.f, 0.f};
    const __half* kb = Kmat + (size_t)row0 * NB;
    #pragma unroll
    for (int c = 0; c < 4; ++c) {
        const int col = (c << 9) + (l << 3);           // lane covers 4 chunks of 8 cols
        const int phys = col + ((col >> 3) << 2);      // padded LDS index
        f32x4 s0 = *(const f32x4*)&sv[phys];
        f32x4 s1 = *(const f32x4*)&sv[phys + 4];
        #pragma unroll
        for (int r = 0; r < 2; ++r) {
            Uh uu; uu.f = *(const f32x4*)(kb + (size_t)r * NB + col);   // plain cached K loads
            float2 f0 = __half22float2(uu.h[0]);
            float2 f1 = __half22float2(uu.h[1]);
            float2 f2 = __half22float2(uu.h[2]);
            float2 f3 = __half22float2(uu.h[3]);
            acc[r] = fmaf(f0.x, s0.x, acc[r]);
            acc[r] = fmaf(f0.y, s0.y, acc[r]);
            acc[r] = fmaf(f1.x, s0.z, acc[r]);
            acc[r] = fmaf(f1.y, s0.w, acc[r]);
            acc[r] = fmaf(f2.x, s1.x, acc[r]);
            acc[r] = fmaf(f2.y, s1.y, acc[r]);
            acc[r] = fmaf(f3.x, s1.z, acc[r]);
            acc[r] = fmaf(f3.y, s1.w, acc[r]);
        }
    }
    #pragma unroll
    for (int r = 0; r < 2; ++r) {
        #pragma unroll
        for (int off = 32; off; off >>= 1) acc[r] += __shfl_down(acc[r], off, 64);
    }
    if (l == 0) {
        f32x2 o;
        o[0] = ab / acc[0]; o[1] = ab / acc[1];
        asm volatile("global_store_dwordx2 %1, %0, off sc0 sc1"
                     :: "v"(o), "v"(xout + row0) : "memory");
    }
    asm volatile("s_waitcnt vmcnt(0)" ::: "memory");   // wave-wide drain before the barrier
}

// ---------------- persistent Sinkhorn: 100 x { v = b/(K^T u); u = a/(K v) } ----------------
// 256 blocks x 4 waves x 2 rows (full chip). Arrivals are single stores to per-block
// flags (monotonic, no RMW, no acquire/release -> no L2 invalidates ever).
__global__ __launch_bounds__(256, 1) void sinkhorn_k(
        const __half* __restrict__ Kr, const __half* __restrict__ Kc,
        float* __restrict__ u, float* __restrict__ v,
        unsigned* __restrict__ flags) {
    __shared__ __align__(16) float sv[3072];   // 2048 floats, padded (i + i/8*4)
    const int tid = threadIdx.x, bid = blockIdx.x;
    const int w = tid >> 6, l = tid & 63;
    const int row0 = (bid << 3) + (w << 1);    // 8 rows/block, 2 rows/wave
    const float ab = 1.0f / NB;
    unsigned* myflag = flags + (bid << 2);     // 16B apart
    for (int it = 0; it < NITER; ++it) {
        // ---- v-step: v = b / (K^T u); needs u@it (phase 2it) ----
        wait_phase(flags, w, l, 2 * it);
        __syncthreads();                       // release block
        stage(u, sv, tid);
        __syncthreads();
        half_step(Kc, v, sv, row0, ab, l);     // compute + store + wave drain
        __syncthreads();                       // all waves' stores drained
        if (tid == 0) {
            unsigned ph = 2 * it + 1;
            asm volatile("global_store_dword %1, %0, off sc0 sc1"
                         :: "v"(ph), "v"(myflag) : "memory");
        }
        // ---- u-step: u = a / (K v); needs v@it+1 (phase 2it+1) ----
        wait_phase(flags, w, l, 2 * it + 1);
        __syncthreads();
        stage(v, sv, tid);
        __syncthreads();
        half_step(Kr, u, sv, row0, ab, l);
        __syncthreads();
        if (tid == 0) {
            unsigned ph = 2 * it + 2;
            asm volatile("global_store_dword %1, %0, off sc0 sc1"
                         :: "v"(ph), "v"(myflag) : "memory");
        }
    }
}

// ---------------- loss: -(1/B) * sum_i [log u_i + log v_i + log K_ii] - log(2^14) ----------------
__global__ void loss_k(const float* __restrict__ u, const float* __restrict__ v,
                       const float* __restrict__ diagMd, const unsigned* __restrict__ maxbits,
                       float* __restrict__ out) {
    int tid = threadIdx.x;
    float mx = __uint_as_float(*maxbits);
    float cc = 1.0f / (mx * EPS);
    double s = 0.0;
    for (int i = tid; i < NB; i += 256)
        s += (double)(logf(u[i]) + logf(v[i]) - diagMd[i] * cc);
    #pragma unroll
    for (int off = 32; off; off >>= 1) s += __shfl_down(s, off, 64);
    __shared__ double red[4];
    if ((tid & 63) == 0) red[tid >> 6] = s;
    __syncthreads();
    if (tid == 0)
        out[0] = (float)(-(red[0] + red[1] + red[2] + red[3]) / (double)NB - LOG_KSCALE);
}

// ---------------- launch ----------------
extern "C" void kernel_launch(void* const* d_in, const int* in_sizes, int n_in,
                              void* d_out, int out_size, void* d_ws, size_t ws_size,
                              hipStream_t stream) {
    const float* audio = (const float*)d_in[0];
    const float* text  = (const float*)d_in[1];
    const float* L     = (const float*)d_in[2];
    char* ws = (char*)d_ws;
    float*    w       = (float*)(ws + 0);
    float*    aw      = (float*)(ws + 4096);
    float*    tw      = (float*)(ws + 12288);
    float*    u       = (float*)(ws + 20480);
    float*    v       = (float*)(ws + 28672);
    float*    diagMd  = (float*)(ws + 36864);
    unsigned* maxbits = (unsigned*)(ws + 45056);
    unsigned* flags   = (unsigned*)(ws + 45312);   // 256 flags x 16B = 4KB
    __half*   Md      = (__half*)(ws + 65536);                          // becomes Kr
    __half*   MdT     = (__half*)(ws + 65536 + (size_t)NB * NB * 2);    // becomes Kc

    prep_k<<<8, 256, 0, stream>>>(L, w, u, v, maxbits, flags);
    rows_k<<<NB, 256, 0, stream>>>(audio, text, w, aw, tw);
    gemm_mdist<<<dim3(16, 16), 256, 0, stream>>>(text, audio, w, tw, aw, Md, MdT, diagMd, maxbits);
    expconv_k<<<4096, 256, 0, stream>>>(Md, maxbits);   // Md & MdT contiguous: 2*NB*NB halfs
    sinkhorn_k<<<SBLK, 256, 0, stream>>>(Md, MdT, u, v, flags);
    loss_k<<<1, 256, 0, stream>>>(u, v, diagMd, maxbits, (float*)d_out);
}

// Round 11
// 721.870 us; speedup vs baseline: 1.3683x; 1.0546x over previous
//
#include <hip/hip_runtime.h>
#include <hip/hip_fp16.h>
#include <math.h>

// Problem constants
#define NB 2048      // batch
#define ND 1024      // dim
#define EPS 0.05f
#define NITER 100
#define SBLK 256     // sinkhorn blocks x 256 threads; 8 rows/block, full chip
#define KSCALE 16384.0f               // 2^14 — pulls f16 K into normal range
#define LOG_KSCALE 9.704060527839234  // log(2^14)

typedef float f32x4 __attribute__((ext_vector_type(4)));
typedef float f32x2 __attribute__((ext_vector_type(2)));
typedef short s16x8 __attribute__((ext_vector_type(8)));
typedef unsigned short u16x4 __attribute__((ext_vector_type(4)));
union Uh { f32x4 f; __half2 h[4]; };

// ---------------- prep: w = nan_to_num(diag(L)), init u/v, zero flags+max ----------------
__global__ void prep_k(const float* __restrict__ L, float* __restrict__ w,
                       float* __restrict__ u, float* __restrict__ v,
                       unsigned* __restrict__ maxbits, unsigned* __restrict__ flags) {
    int gtid = blockIdx.x * 256 + threadIdx.x;   // 0..2047
    if (gtid < ND) {
        float x = L[(size_t)gtid * (ND + 1)];
        if (x != x) x = 0.f;
        else if (fabsf(x) == INFINITY) x = (x > 0.f) ? 3.4028235e38f : -3.4028235e38f;
        w[gtid] = x;
    }
    u[gtid] = 1.0f / NB;
    v[gtid] = 1.0f / NB;
    if (gtid == 0) *maxbits = 0u;
    if (gtid < 1024) flags[gtid] = 0u;   // 256 flags x 16B
}

// ---------------- per-row weighted squared norms ----------------
__global__ __launch_bounds__(256) void rows_k(const float* __restrict__ audio,
                                              const float* __restrict__ text,
                                              const float* __restrict__ w,
                                              float* __restrict__ aw, float* __restrict__ tw) {
    int r = blockIdx.x, tid = threadIdx.x;
    float4 wv = *(const float4*)&w[tid * 4];
    float4 a4 = *(const float4*)&audio[(size_t)r * ND + tid * 4];
    float4 t4 = *(const float4*)&text[(size_t)r * ND + tid * 4];
    float sa = a4.x * a4.x * wv.x + a4.y * a4.y * wv.y + a4.z * a4.z * wv.z + a4.w * a4.w * wv.w;
    float st = t4.x * t4.x * wv.x + t4.y * t4.y * wv.y + t4.z * t4.z * wv.z + t4.w * t4.w * wv.w;
    #pragma unroll
    for (int off = 32; off; off >>= 1) {
        sa += __shfl_down(sa, off, 64);
        st += __shfl_down(st, off, 64);
    }
    __shared__ float red[8];
    if ((tid & 63) == 0) { red[tid >> 6] = sa; red[4 + (tid >> 6)] = st; }
    __syncthreads();
    if (tid == 0) {
        aw[r] = red[0] + red[1] + red[2] + red[3];
        tw[r] = red[4] + red[5] + red[6] + red[7];
    }
}

// ---------------- f32 -> bf16 round-to-nearest-even (bit trick) ----------------
__device__ __forceinline__ unsigned short f2bf(float x) {
    unsigned uu = __float_as_uint(x);
    return (unsigned short)((uu + 0x7FFFu + ((uu >> 16) & 1u)) >> 16);
}

// ---------------- bf16 MFMA GEMM -> M_dist (f16, row + col major) + global max ----------------
__global__ __launch_bounds__(256) void gemm_mdist(
        const float* __restrict__ Tm, const float* __restrict__ Am,
        const float* __restrict__ wd, const float* __restrict__ tw, const float* __restrict__ aw,
        __half* __restrict__ Md, __half* __restrict__ MdT,
        float* __restrict__ diagMd, unsigned* __restrict__ maxbits) {
    __shared__ __align__(16) unsigned char smem[38912];
    float* wl = (float*)(smem + 34816);
    const int t = threadIdx.x;
    const int row0 = blockIdx.y * 128, col0 = blockIdx.x * 128;
    *(f32x4*)&wl[t * 4] = *(const f32x4*)&wd[t * 4];
    const int wv = t >> 6;                 // wave 0..3
    const int wr = wv >> 1, wc = wv & 1;   // 2x2 wave grid, 64x64 out each
    const int l = t & 63, lr = l & 15, kg = l >> 4;
    const int trow = t >> 4, tk4 = t & 15;
    const int px = (((tk4 >> 1) ^ (trow & 7)) << 4) + ((tk4 & 1) << 3);
    f32x4 acc[4][4];
    #pragma unroll
    for (int m = 0; m < 4; ++m)
        #pragma unroll
        for (int n = 0; n < 4; ++n) acc[m][n] = (f32x4){0.f, 0.f, 0.f, 0.f};
    __syncthreads();
    const float* tp = Tm + (size_t)(row0 + trow) * ND + tk4 * 4;
    const float* ap = Am + (size_t)(col0 + trow) * ND + tk4 * 4;
    for (int k0 = 0; k0 < ND; k0 += 64) {
        f32x4 wv4 = *(const f32x4*)&wl[k0 + tk4 * 4];
        __syncthreads();
        #pragma unroll
        for (int s = 0; s < 8; ++s) {
            f32x4 tv = *(const f32x4*)(tp + (size_t)(s * 16) * ND + k0);
            f32x4 av = *(const f32x4*)(ap + (size_t)(s * 16) * ND + k0);
            tv *= wv4;
            u16x4 tb, ab;
            tb[0] = f2bf(tv[0]); tb[1] = f2bf(tv[1]); tb[2] = f2bf(tv[2]); tb[3] = f2bf(tv[3]);
            ab[0] = f2bf(av[0]); ab[1] = f2bf(av[1]); ab[2] = f2bf(av[2]); ab[3] = f2bf(av[3]);
            const int rb = (s * 16 + trow) * 128 + px;
            *(u16x4*)(smem + rb) = tb;
            *(u16x4*)(smem + 16384 + rb) = ab;
        }
        __syncthreads();
        #pragma unroll
        for (int kk = 0; kk < 2; ++kk) {
            const int sl = (((kk << 2) + kg) ^ (lr & 7)) << 4;
            s16x8 af[4], bfr[4];
            #pragma unroll
            for (int m = 0; m < 4; ++m)
                af[m] = *(const s16x8*)(smem + (wr * 64 + m * 16 + lr) * 128 + sl);
            #pragma unroll
            for (int n = 0; n < 4; ++n)
                bfr[n] = *(const s16x8*)(smem + 16384 + (wc * 64 + n * 16 + lr) * 128 + sl);
            #pragma unroll
            for (int m = 0; m < 4; ++m)
                #pragma unroll
                for (int n = 0; n < 4; ++n)
                    acc[m][n] = __builtin_amdgcn_mfma_f32_16x16x32_bf16(af[m], bfr[n], acc[m][n], 0, 0, 0);
        }
    }
    __syncthreads();
    unsigned short* tr = (unsigned short*)smem;
    unsigned short* mdp = (unsigned short*)Md;
    float lmax = 0.f;
    #pragma unroll
    for (int m = 0; m < 4; ++m) {
        #pragma unroll
        for (int r = 0; r < 4; ++r) {
            const int li = wr * 64 + m * 16 + kg * 4 + r;
            const int i = row0 + li;
            const float twi = tw[i];
            #pragma unroll
            for (int n = 0; n < 4; ++n) {
                const int lj = wc * 64 + n * 16 + lr;
                const int j = col0 + lj;
                float md = twi + aw[j] - 2.0f * acc[m][n][r];
                md = sqrtf(fmaxf(md, 0.f));
                lmax = fmaxf(lmax, md);
                const unsigned short hb = __half_as_ushort(__float2half(md));
                mdp[(size_t)i * NB + j] = hb;
                tr[lj * 136 + li] = hb;
                if (i == j) diagMd[i] = md;
            }
        }
    }
    __syncthreads();
    {
        const int jj = t >> 1, ih = (t & 1) * 64;
        unsigned short* dst = (unsigned short*)MdT + (size_t)(col0 + jj) * NB + row0 + ih;
        #pragma unroll
        for (int x = 0; x < 8; ++x)
            *(s16x8*)(dst + x * 8) = *(const s16x8*)&tr[jj * 136 + ih + x * 8];
    }
    #pragma unroll
    for (int off = 32; off; off >>= 1) lmax = fmaxf(lmax, __shfl_down(lmax, off, 64));
    float* red = (float*)(smem + 34816);
    if (l == 0) red[t >> 6] = lmax;
    __syncthreads();
    if (t == 0) {
        float m2 = fmaxf(fmaxf(red[0], red[1]), fmaxf(red[2], red[3]));
        atomicMax(maxbits, __float_as_uint(m2));
    }
}

// ---------------- convert M_dist -> K' = exp(-md/(mx*eps)) * 2^14, in place (both majors) ----------------
__global__ __launch_bounds__(256) void expconv_k(__half* __restrict__ Kall,
                                                 const unsigned* __restrict__ maxbits) {
    const float mx = __uint_as_float(*maxbits);
    const float cc = -1.0f / (mx * EPS);
    size_t idx = ((size_t)blockIdx.x * 256 + threadIdx.x) << 3;   // 8 halfs per thread
    Uh uu; uu.f = *(const f32x4*)(Kall + idx);
    #pragma unroll
    for (int q = 0; q < 4; ++q) {
        float2 f = __half22float2(uu.h[q]);
        f.x = __expf(f.x * cc) * KSCALE;
        f.y = __expf(f.y * cc) * KSCALE;
        uu.h[q] = __floats2half2_rn(f.x, f.y);
    }
    *(f32x4*)(Kall + idx) = uu.f;
}

// ---------------- store-broadcast barrier: 256 flags (16B apart), no RMW anywhere ----------------
// wave 0 polls: lane l loads flags l, l+64, l+128, l+192; all >= ph -> done.
__device__ __forceinline__ void wait_phase(const unsigned* __restrict__ flags, int w, int l,
                                           unsigned ph) {
    if (w == 0) {
        const unsigned* p = flags + (l << 2);
        for (;;) {
            unsigned f0, f1, f2, f3;
            asm volatile("global_load_dword %0, %4, off sc0 sc1\n\t"
                         "global_load_dword %1, %5, off sc0 sc1\n\t"
                         "global_load_dword %2, %6, off sc0 sc1\n\t"
                         "global_load_dword %3, %7, off sc0 sc1\n\t"
                         "s_waitcnt vmcnt(0)"
                         : "=&v"(f0), "=&v"(f1), "=&v"(f2), "=&v"(f3)
                         : "v"(p), "v"(p + 256), "v"(p + 512), "v"(p + 768) : "memory");
            if (__all((f0 >= ph) && (f1 >= ph) && (f2 >= ph) && (f3 >= ph))) break;
            __builtin_amdgcn_s_sleep(1);
        }
    }
}

// ---------------- LLC-coherent 32B staged load into padded LDS ----------------
__device__ __forceinline__ void stage(const float* __restrict__ src, float* sv, int tid) {
    const float* p0 = src + (tid << 3);
    f32x4 r0, r1;
    asm volatile("global_load_dwordx4 %0, %2, off sc0 sc1\n\t"
                 "global_load_dwordx4 %1, %3, off sc0 sc1\n\t"
                 "s_waitcnt vmcnt(0)"
                 : "=&v"(r0), "=&v"(r1) : "v"(p0), "v"(p0 + 4) : "memory");
    // padded LDS layout: logical i -> i + (i/8)*4  (conflict-free b128 reads)
    *(f32x4*)&sv[tid * 12] = r0;
    *(f32x4*)&sv[tid * 12 + 4] = r1;
}

// ---------------- one half-step from register-resident K: xout[row0..1] = ab/(Kreg . sv) ----------------
__device__ __forceinline__ void half_step_reg(const f32x4 (&kreg)[2][8],
                                              float* __restrict__ xout,
                                              const float* sv, int row0, float ab, int l) {
    float acc0 = 0.f, acc1 = 0.f;
    #pragma unroll
    for (int c = 0; c < 4; ++c) {
        const int col = (c << 9) + (l << 3);           // lane covers 4 chunks of 8 cols
        const int phys = col + ((col >> 3) << 2);      // padded LDS index
        f32x4 s0 = *(const f32x4*)&sv[phys];
        f32x4 s1 = *(const f32x4*)&sv[phys + 4];
        #pragma unroll
        for (int q = 0; q < 4; ++q) {
            acc0 = fmaf(kreg[0][2 * c][q], s0[q], acc0);
            acc0 = fmaf(kreg[0][2 * c + 1][q], s1[q], acc0);
            acc1 = fmaf(kreg[1][2 * c][q], s0[q], acc1);
            acc1 = fmaf(kreg[1][2 * c + 1][q], s1[q], acc1);
        }
    }
    #pragma unroll
    for (int off = 32; off; off >>= 1) {
        acc0 += __shfl_down(acc0, off, 64);
        acc1 += __shfl_down(acc1, off, 64);
    }
    if (l == 0) {
        f32x2 o;
        o[0] = ab / acc0; o[1] = ab / acc1;
        asm volatile("global_store_dwordx2 %1, %0, off sc0 sc1"
                     :: "v"(o), "v"(xout + row0) : "memory");
    }
    asm volatile("s_waitcnt vmcnt(0)" ::: "memory");   // wave-wide drain before the barrier
}

// ---------------- persistent Sinkhorn: 100 x { v = b/(K^T u); u = a/(K v) } ----------------
// 256 blocks x 4 waves x 2 rows (full chip). K preloaded into registers (128 VGPR/thread):
// the 200-step loop does ZERO global K loads. Store-only flag barrier (no RMW, no acq/rel).
__global__ __launch_bounds__(256, 1) void sinkhorn_k(
        const __half* __restrict__ Kr, const __half* __restrict__ Kc,
        float* __restrict__ u, float* __restrict__ v,
        unsigned* __restrict__ flags) {
    __shared__ __align__(16) float sv[3072];   // 2048 floats, padded (i + i/8*4)
    const int tid = threadIdx.x, bid = blockIdx.x;
    const int w = tid >> 6, l = tid & 63;
    const int row0 = (bid << 3) + (w << 1);    // 8 rows/block, 2 rows/wave
    const float ab = 1.0f / NB;
    unsigned* myflag = flags + (bid << 2);     // 16B apart
    // ---- one-time K preload: 2 rows x 32 halfs per matrix per thread -> f32 regs ----
    f32x4 kc[2][8], kr[2][8];
    #pragma unroll
    for (int r = 0; r < 2; ++r) {
        const __half* pc = Kc + (size_t)(row0 + r) * NB;
        const __half* pr = Kr + (size_t)(row0 + r) * NB;
        #pragma unroll
        for (int c = 0; c < 4; ++c) {
            const int col = (c << 9) + (l << 3);
            Uh a; a.f = *(const f32x4*)(pc + col);
            Uh b; b.f = *(const f32x4*)(pr + col);
            float2 a0 = __half22float2(a.h[0]), a1 = __half22float2(a.h[1]);
            float2 a2 = __half22float2(a.h[2]), a3 = __half22float2(a.h[3]);
            float2 b0 = __half22float2(b.h[0]), b1 = __half22float2(b.h[1]);
            float2 b2 = __half22float2(b.h[2]), b3 = __half22float2(b.h[3]);
            kc[r][2 * c]     = (f32x4){a0.x, a0.y, a1.x, a1.y};
            kc[r][2 * c + 1] = (f32x4){a2.x, a2.y, a3.x, a3.y};
            kr[r][2 * c]     = (f32x4){b0.x, b0.y, b1.x, b1.y};
            kr[r][2 * c + 1] = (f32x4){b2.x, b2.y, b3.x, b3.y};
        }
    }
    for (int it = 0; it < NITER; ++it) {
        // ---- v-step: v = b / (K^T u); needs u@it (phase 2it) ----
        wait_phase(flags, w, l, 2 * it);
        __syncthreads();                       // release block
        stage(u, sv, tid);
        __syncthreads();
        half_step_reg(kc, v, sv, row0, ab, l); // compute + store + wave drain
        __syncthreads();                       // all waves' stores drained
        if (tid == 0) {
            unsigned ph = 2 * it + 1;
            asm volatile("global_store_dword %1, %0, off sc0 sc1"
                         :: "v"(ph), "v"(myflag) : "memory");
        }
        // ---- u-step: u = a / (K v); needs v@it+1 (phase 2it+1) ----
        wait_phase(flags, w, l, 2 * it + 1);
        __syncthreads();
        stage(v, sv, tid);
        __syncthreads();
        half_step_reg(kr, u, sv, row0, ab, l);
        __syncthreads();
        if (tid == 0) {
            unsigned ph = 2 * it + 2;
            asm volatile("global_store_dword %1, %0, off sc0 sc1"
                         :: "v"(ph), "v"(myflag) : "memory");
        }
    }
}

// ---------------- loss: -(1/B) * sum_i [log u_i + log v_i + log K_ii] - log(2^14) ----------------
__global__ void loss_k(const float* __restrict__ u, const float* __restrict__ v,
                       const float* __restrict__ diagMd, const unsigned* __restrict__ maxbits,
                       float* __restrict__ out) {
    int tid = threadIdx.x;
    float mx = __uint_as_float(*maxbits);
    float cc = 1.0f / (mx * EPS);
    double s = 0.0;
    for (int i = tid; i < NB; i += 256)
        s += (double)(logf(u[i]) + logf(v[i]) - diagMd[i] * cc);
    #pragma unroll
    for (int off = 32; off; off >>= 1) s += __shfl_down(s, off, 64);
    __shared__ double red[4];
    if ((tid & 63) == 0) red[tid >> 6] = s;
    __syncthreads();
    if (tid == 0)
        out[0] = (float)(-(red[0] + red[1] + red[2] + red[3]) / (double)NB - LOG_KSCALE);
}

// ---------------- launch ----------------
extern "C" void kernel_launch(void* const* d_in, const int* in_sizes, int n_in,
                              void* d_out, int out_size, void* d_ws, size_t ws_size,
                              hipStream_t stream) {
    const float* audio = (const float*)d_in[0];
    const float* text  = (const float*)d_in[1];
    const float* L     = (const float*)d_in[2];
    char* ws = (char*)d_ws;
    float*    w       = (float*)(ws + 0);
    float*    aw      = (float*)(ws + 4096);
    float*    tw      = (float*)(ws + 12288);
    float*    u       = (float*)(ws + 20480);
    float*    v       = (float*)(ws + 28672);
    float*    diagMd  = (float*)(ws + 36864);
    unsigned* maxbits = (unsigned*)(ws + 45056);
    unsigned* flags   = (unsigned*)(ws + 45312);   // 256 flags x 16B = 4KB
    __half*   Md      = (__half*)(ws + 65536);                          // becomes Kr
    __half*   MdT     = (__half*)(ws + 65536 + (size_t)NB * NB * 2);    // becomes Kc

    prep_k<<<8, 256, 0, stream>>>(L, w, u, v, maxbits, flags);
    rows_k<<<NB, 256, 0, stream>>>(audio, text, w, aw, tw);
    gemm_mdist<<<dim3(16, 16), 256, 0, stream>>>(text, audio, w, tw, aw, Md, MdT, diagMd, maxbits);
    expconv_k<<<4096, 256, 0, stream>>>(Md, maxbits);   // Md & MdT contiguous: 2*NB*NB halfs
    sinkhorn_k<<<SBLK, 256, 0, stream>>>(Md, MdT, u, v, flags);
    loss_k<<<1, 256, 0, stream>>>(u, v, diagMd, maxbits, (float*)d_out);
}

// Round 12
// 713.501 us; speedup vs baseline: 1.3843x; 1.0117x over previous
//
#include <hip/hip_runtime.h>
#include <hip/hip_fp16.h>
#include <math.h>

// Problem constants
#define NB 2048      // batch
#define ND 1024      // dim
#define EPS 0.05f
#define NITER 100
#define SBLK 256     // sinkhorn blocks x 256 threads; 8 rows/block, full chip

typedef float f32x4 __attribute__((ext_vector_type(4)));
typedef float f32x2 __attribute__((ext_vector_type(2)));
typedef short s16x8 __attribute__((ext_vector_type(8)));
typedef unsigned short u16x4 __attribute__((ext_vector_type(4)));
union Uh { f32x4 f; __half2 h[4]; };

// ---------------- prep: w = nan_to_num(diag(L)), init u/v, zero flags+max ----------------
__global__ void prep_k(const float* __restrict__ L, float* __restrict__ w,
                       float* __restrict__ u, float* __restrict__ v,
                       unsigned* __restrict__ maxbits, unsigned* __restrict__ flags) {
    int gtid = blockIdx.x * 256 + threadIdx.x;   // 0..2047
    if (gtid < ND) {
        float x = L[(size_t)gtid * (ND + 1)];
        if (x != x) x = 0.f;
        else if (fabsf(x) == INFINITY) x = (x > 0.f) ? 3.4028235e38f : -3.4028235e38f;
        w[gtid] = x;
    }
    u[gtid] = 1.0f / NB;
    v[gtid] = 1.0f / NB;
    if (gtid == 0) *maxbits = 0u;
    if (gtid < 1024) flags[gtid] = 0u;   // 256 flags x 16B
}

// ---------------- per-row weighted squared norms ----------------
__global__ __launch_bounds__(256) void rows_k(const float* __restrict__ audio,
                                              const float* __restrict__ text,
                                              const float* __restrict__ w,
                                              float* __restrict__ aw, float* __restrict__ tw) {
    int r = blockIdx.x, tid = threadIdx.x;
    float4 wv = *(const float4*)&w[tid * 4];
    float4 a4 = *(const float4*)&audio[(size_t)r * ND + tid * 4];
    float4 t4 = *(const float4*)&text[(size_t)r * ND + tid * 4];
    float sa = a4.x * a4.x * wv.x + a4.y * a4.y * wv.y + a4.z * a4.z * wv.z + a4.w * a4.w * wv.w;
    float st = t4.x * t4.x * wv.x + t4.y * t4.y * wv.y + t4.z * t4.z * wv.z + t4.w * t4.w * wv.w;
    #pragma unroll
    for (int off = 32; off; off >>= 1) {
        sa += __shfl_down(sa, off, 64);
        st += __shfl_down(st, off, 64);
    }
    __shared__ float red[8];
    if ((tid & 63) == 0) { red[tid >> 6] = sa; red[4 + (tid >> 6)] = st; }
    __syncthreads();
    if (tid == 0) {
        aw[r] = red[0] + red[1] + red[2] + red[3];
        tw[r] = red[4] + red[5] + red[6] + red[7];
    }
}

// ---------------- f32 -> bf16 round-to-nearest-even (bit trick) ----------------
__device__ __forceinline__ unsigned short f2bf(float x) {
    unsigned uu = __float_as_uint(x);
    return (unsigned short)((uu + 0x7FFFu + ((uu >> 16) & 1u)) >> 16);
}

// ---------------- bf16 MFMA GEMM -> M_dist (f16, row + col major) + global max ----------------
__global__ __launch_bounds__(256) void gemm_mdist(
        const float* __restrict__ Tm, const float* __restrict__ Am,
        const float* __restrict__ wd, const float* __restrict__ tw, const float* __restrict__ aw,
        __half* __restrict__ Md, __half* __restrict__ MdT,
        float* __restrict__ diagMd, unsigned* __restrict__ maxbits) {
    __shared__ __align__(16) unsigned char smem[38912];
    float* wl = (float*)(smem + 34816);
    const int t = threadIdx.x;
    const int row0 = blockIdx.y * 128, col0 = blockIdx.x * 128;
    *(f32x4*)&wl[t * 4] = *(const f32x4*)&wd[t * 4];
    const int wv = t >> 6;                 // wave 0..3
    const int wr = wv >> 1, wc = wv & 1;   // 2x2 wave grid, 64x64 out each
    const int l = t & 63, lr = l & 15, kg = l >> 4;
    const int trow = t >> 4, tk4 = t & 15;
    const int px = (((tk4 >> 1) ^ (trow & 7)) << 4) + ((tk4 & 1) << 3);
    f32x4 acc[4][4];
    #pragma unroll
    for (int m = 0; m < 4; ++m)
        #pragma unroll
        for (int n = 0; n < 4; ++n) acc[m][n] = (f32x4){0.f, 0.f, 0.f, 0.f};
    __syncthreads();
    const float* tp = Tm + (size_t)(row0 + trow) * ND + tk4 * 4;
    const float* ap = Am + (size_t)(col0 + trow) * ND + tk4 * 4;
    for (int k0 = 0; k0 < ND; k0 += 64) {
        f32x4 wv4 = *(const f32x4*)&wl[k0 + tk4 * 4];
        __syncthreads();
        #pragma unroll
        for (int s = 0; s < 8; ++s) {
            f32x4 tv = *(const f32x4*)(tp + (size_t)(s * 16) * ND + k0);
            f32x4 av = *(const f32x4*)(ap + (size_t)(s * 16) * ND + k0);
            tv *= wv4;
            u16x4 tb, ab;
            tb[0] = f2bf(tv[0]); tb[1] = f2bf(tv[1]); tb[2] = f2bf(tv[2]); tb[3] = f2bf(tv[3]);
            ab[0] = f2bf(av[0]); ab[1] = f2bf(av[1]); ab[2] = f2bf(av[2]); ab[3] = f2bf(av[3]);
            const int rb = (s * 16 + trow) * 128 + px;
            *(u16x4*)(smem + rb) = tb;
            *(u16x4*)(smem + 16384 + rb) = ab;
        }
        __syncthreads();
        #pragma unroll
        for (int kk = 0; kk < 2; ++kk) {
            const int sl = (((kk << 2) + kg) ^ (lr & 7)) << 4;
            s16x8 af[4], bfr[4];
            #pragma unroll
            for (int m = 0; m < 4; ++m)
                af[m] = *(const s16x8*)(smem + (wr * 64 + m * 16 + lr) * 128 + sl);
            #pragma unroll
            for (int n = 0; n < 4; ++n)
                bfr[n] = *(const s16x8*)(smem + 16384 + (wc * 64 + n * 16 + lr) * 128 + sl);
            #pragma unroll
            for (int m = 0; m < 4; ++m)
                #pragma unroll
                for (int n = 0; n < 4; ++n)
                    acc[m][n] = __builtin_amdgcn_mfma_f32_16x16x32_bf16(af[m], bfr[n], acc[m][n], 0, 0, 0);
        }
    }
    __syncthreads();
    unsigned short* tr = (unsigned short*)smem;
    unsigned short* mdp = (unsigned short*)Md;
    float lmax = 0.f;
    #pragma unroll
    for (int m = 0; m < 4; ++m) {
        #pragma unroll
        for (int r = 0; r < 4; ++r) {
            const int li = wr * 64 + m * 16 + kg * 4 + r;
            const int i = row0 + li;
            const float twi = tw[i];
            #pragma unroll
            for (int n = 0; n < 4; ++n) {
                const int lj = wc * 64 + n * 16 + lr;
                const int j = col0 + lj;
                float md = twi + aw[j] - 2.0f * acc[m][n][r];
                md = sqrtf(fmaxf(md, 0.f));
                lmax = fmaxf(lmax, md);
                const unsigned short hb = __half_as_ushort(__float2half(md));
                mdp[(size_t)i * NB + j] = hb;
                tr[lj * 136 + li] = hb;
                if (i == j) diagMd[i] = md;
            }
        }
    }
    __syncthreads();
    {
        const int jj = t >> 1, ih = (t & 1) * 64;
        unsigned short* dst = (unsigned short*)MdT + (size_t)(col0 + jj) * NB + row0 + ih;
        #pragma unroll
        for (int x = 0; x < 8; ++x)
            *(s16x8*)(dst + x * 8) = *(const s16x8*)&tr[jj * 136 + ih + x * 8];
    }
    #pragma unroll
    for (int off = 32; off; off >>= 1) lmax = fmaxf(lmax, __shfl_down(lmax, off, 64));
    float* red = (float*)(smem + 34816);
    if (l == 0) red[t >> 6] = lmax;
    __syncthreads();
    if (t == 0) {
        float m2 = fmaxf(fmaxf(red[0], red[1]), fmaxf(red[2], red[3]));
        atomicMax(maxbits, __float_as_uint(m2));
    }
}

// ---------------- store-broadcast barrier poll: 256 flags (16B apart), no RMW ----------------
// ALL waves poll: lane l loads flags l, l+64, l+128, l+192; all >= ph -> done.
__device__ __forceinline__ void wait_phase(const unsigned* __restrict__ flags, int l,
                                           unsigned ph) {
    const unsigned* p = flags + (l << 2);
    for (;;) {
        unsigned f0, f1, f2, f3;
        asm volatile("global_load_dword %0, %4, off sc0 sc1\n\t"
                     "global_load_dword %1, %5, off sc0 sc1\n\t"
                     "global_load_dword %2, %6, off sc0 sc1\n\t"
                     "global_load_dword %3, %7, off sc0 sc1\n\t"
                     "s_waitcnt vmcnt(0)"
                     : "=&v"(f0), "=&v"(f1), "=&v"(f2), "=&v"(f3)
                     : "v"(p), "v"(p + 256), "v"(p + 512), "v"(p + 768) : "memory");
        if (__all((f0 >= ph) && (f1 >= ph) && (f2 >= ph) && (f3 >= ph))) break;
        __builtin_amdgcn_s_sleep(1);
    }
}

// ---------------- per-wave half-step, all in registers: load x -> dot with Kreg -> store ----------------
// Each wave loads the FULL 2048-vector into regs (lane l: cols (c<<9)+(l<<3), c=0..3).
__device__ __forceinline__ void half_step_reg(const f32x4 (&kreg)[2][8],
                                              const float* __restrict__ xin,
                                              float* __restrict__ xout,
                                              int row0, float ab, int l) {
    const float* p0 = xin + (l << 3);
    f32x4 x[8];
    asm volatile("global_load_dwordx4 %0, %8, off sc0 sc1\n\t"
                 "global_load_dwordx4 %1, %9, off sc0 sc1\n\t"
                 "global_load_dwordx4 %2, %10, off sc0 sc1\n\t"
                 "global_load_dwordx4 %3, %11, off sc0 sc1\n\t"
                 "global_load_dwordx4 %4, %12, off sc0 sc1\n\t"
                 "global_load_dwordx4 %5, %13, off sc0 sc1\n\t"
                 "global_load_dwordx4 %6, %14, off sc0 sc1\n\t"
                 "global_load_dwordx4 %7, %15, off sc0 sc1\n\t"
                 "s_waitcnt vmcnt(0)"
                 : "=&v"(x[0]), "=&v"(x[1]), "=&v"(x[2]), "=&v"(x[3]),
                   "=&v"(x[4]), "=&v"(x[5]), "=&v"(x[6]), "=&v"(x[7])
                 : "v"(p0), "v"(p0 + 4), "v"(p0 + 512), "v"(p0 + 516),
                   "v"(p0 + 1024), "v"(p0 + 1028), "v"(p0 + 1536), "v"(p0 + 1540)
                 : "memory");
    float acc0 = 0.f, acc1 = 0.f;
    #pragma unroll
    for (int j = 0; j < 8; ++j) {
        #pragma unroll
        for (int q = 0; q < 4; ++q) {
            acc0 = fmaf(kreg[0][j][q], x[j][q], acc0);
            acc1 = fmaf(kreg[1][j][q], x[j][q], acc1);
        }
    }
    #pragma unroll
    for (int off = 32; off; off >>= 1) {
        acc0 += __shfl_down(acc0, off, 64);
        acc1 += __shfl_down(acc1, off, 64);
    }
    if (l == 0) {
        f32x2 o;
        o[0] = ab / acc0; o[1] = ab / acc1;
        asm volatile("global_store_dwordx2 %1, %0, off sc0 sc1"
                     :: "v"(o), "v"(xout + row0) : "memory");
    }
    asm volatile("s_waitcnt vmcnt(0)" ::: "memory");   // wave-wide drain before flag
}

// ---------------- persistent Sinkhorn: 100 x { v = b/(K^T u); u = a/(K v) } ----------------
// 256 blocks x 4 waves x 2 rows. K = exp(-md/(mx*eps)) computed ONCE into registers
// (128 VGPR/thread); per half-step: per-wave poll -> direct reg load of u/v -> FMA ->
// store -> one syncthreads -> per-block flag store. No LDS, no RMW, no acq/rel.
__global__ __launch_bounds__(256, 1) void sinkhorn_k(
        const __half* __restrict__ Mdr, const __half* __restrict__ Mdc,
        float* __restrict__ u, float* __restrict__ v,
        const unsigned* __restrict__ maxbits, unsigned* __restrict__ flags) {
    const int tid = threadIdx.x, bid = blockIdx.x;
    const int w = tid >> 6, l = tid & 63;
    const int row0 = (bid << 3) + (w << 1);    // 8 rows/block, 2 rows/wave
    const float ab = 1.0f / NB;
    unsigned* myflag = flags + (bid << 2);     // 16B apart
    const float mx = __uint_as_float(*maxbits);
    const float cc = -1.0f / (mx * EPS);
    // ---- one-time K build: 2 rows x 32 cols per matrix per thread, exp fused, f32 regs ----
    f32x4 kc[2][8], kr[2][8];
    #pragma unroll
    for (int r = 0; r < 2; ++r) {
        const __half* pc = Mdc + (size_t)(row0 + r) * NB;
        const __half* pr = Mdr + (size_t)(row0 + r) * NB;
        #pragma unroll
        for (int c = 0; c < 4; ++c) {
            const int col = (c << 9) + (l << 3);
            Uh a; a.f = *(const f32x4*)(pc + col);
            Uh b; b.f = *(const f32x4*)(pr + col);
            #pragma unroll
            for (int q = 0; q < 4; ++q) {
                float2 fa = __half22float2(a.h[q]);
                float2 fb = __half22float2(b.h[q]);
                kc[r][2 * c + (q >> 1)][(q & 1) * 2]     = __expf(fa.x * cc);
                kc[r][2 * c + (q >> 1)][(q & 1) * 2 + 1] = __expf(fa.y * cc);
                kr[r][2 * c + (q >> 1)][(q & 1) * 2]     = __expf(fb.x * cc);
                kr[r][2 * c + (q >> 1)][(q & 1) * 2 + 1] = __expf(fb.y * cc);
            }
        }
    }
    for (int it = 0; it < NITER; ++it) {
        // ---- v-step: v = b / (K^T u); needs u@it (phase 2it) ----
        wait_phase(flags, l, 2 * it);
        half_step_reg(kc, u, v, row0, ab, l);
        __syncthreads();                       // all waves stored + drained
        if (tid == 0) {
            unsigned ph = 2 * it + 1;
            asm volatile("global_store_dword %1, %0, off sc0 sc1"
                         :: "v"(ph), "v"(myflag) : "memory");
        }
        // ---- u-step: u = a / (K v); needs v@it+1 (phase 2it+1) ----
        wait_phase(flags, l, 2 * it + 1);
        half_step_reg(kr, v, u, row0, ab, l);
        __syncthreads();
        if (tid == 0) {
            unsigned ph = 2 * it + 2;
            asm volatile("global_store_dword %1, %0, off sc0 sc1"
                         :: "v"(ph), "v"(myflag) : "memory");
        }
    }
}

// ---------------- loss: -(1/B) * sum_i [log u_i + log v_i + log K_ii] ----------------
__global__ void loss_k(const float* __restrict__ u, const float* __restrict__ v,
                       const float* __restrict__ diagMd, const unsigned* __restrict__ maxbits,
                       float* __restrict__ out) {
    int tid = threadIdx.x;
    float mx = __uint_as_float(*maxbits);
    float cc = 1.0f / (mx * EPS);
    double s = 0.0;
    for (int i = tid; i < NB; i += 256)
        s += (double)(logf(u[i]) + logf(v[i]) - diagMd[i] * cc);
    #pragma unroll
    for (int off = 32; off; off >>= 1) s += __shfl_down(s, off, 64);
    __shared__ double red[4];
    if ((tid & 63) == 0) red[tid >> 6] = s;
    __syncthreads();
    if (tid == 0)
        out[0] = (float)(-(red[0] + red[1] + red[2] + red[3]) / (double)NB);
}

// ---------------- launch ----------------
extern "C" void kernel_launch(void* const* d_in, const int* in_sizes, int n_in,
                              void* d_out, int out_size, void* d_ws, size_t ws_size,
                              hipStream_t stream) {
    const float* audio = (const float*)d_in[0];
    const float* text  = (const float*)d_in[1];
    const float* L     = (const float*)d_in[2];
    char* ws = (char*)d_ws;
    float*    w       = (float*)(ws + 0);
    float*    aw      = (float*)(ws + 4096);
    float*    tw      = (float*)(ws + 12288);
    float*    u       = (float*)(ws + 20480);
    float*    v       = (float*)(ws + 28672);
    float*    diagMd  = (float*)(ws + 36864);
    unsigned* maxbits = (unsigned*)(ws + 45056);
    unsigned* flags   = (unsigned*)(ws + 45312);   // 256 flags x 16B = 4KB
    __half*   Md      = (__half*)(ws + 65536);                          // md row-major
    __half*   MdT     = (__half*)(ws + 65536 + (size_t)NB * NB * 2);    // md col-major

    prep_k<<<8, 256, 0, stream>>>(L, w, u, v, maxbits, flags);
    rows_k<<<NB, 256, 0, stream>>>(audio, text, w, aw, tw);
    gemm_mdist<<<dim3(16, 16), 256, 0, stream>>>(text, audio, w, tw, aw, Md, MdT, diagMd, maxbits);
    sinkhorn_k<<<SBLK, 256, 0, stream>>>(Md, MdT, u, v, maxbits, flags);
    loss_k<<<1, 256, 0, stream>>>(u, v, diagMd, maxbits, (float*)d_out);
}